// Round 6
// baseline (290.368 us; speedup 1.0000x reference)
//
#include <hip/hip_runtime.h>
#include <math.h>

#define BB 64
#define AA 32
#define KK 50
#define DD 128
#define MAX_KP 50
#define EPS_CS 1e-8f
#define NVEC (3 * BB * AA)   // 6144

__device__ __forceinline__ float dot4(float4 a, float4 b) {
    return a.x * b.x + a.y * b.y + a.z * b.z + a.w * b.w;
}

__global__ void init_kernel(unsigned* __restrict__ cnt) {
    if (threadIdx.x < BB + 1) cnt[threadIdx.x] = 0u;
}

// One 64-lane wave per (tensor, b, a) vector; 2 waves per block (same batch b).
// Embed phase = R5 (two rows per dwordx4 via per-lane addresses, SGPR indices).
// Completion phase: 48th block of batch b computes that batch's cosine
// (register-tiled, LDS-free so embed occupancy is unaffected); 64th batch
// winner reduces the 64 losses with a fixed xor tree -> out[0].
__global__ __launch_bounds__(128) void fused_kernel(
    const int* __restrict__ src, const int* __restrict__ pos,
    const int* __restrict__ neg, const float* __restrict__ table,
    float* __restrict__ embs, unsigned* __restrict__ cnt,
    float* __restrict__ per_batch, float* __restrict__ out)
{
    const int tid = threadIdx.x;
    const int vec = __builtin_amdgcn_readfirstlane(
        (blockIdx.x << 1) | (tid >> 6));           // 0..6143, wave-uniform
    const int t  = vec >> 11;
    const int ba = vec & 2047;
    const int* idx = ((t == 0) ? src : (t == 1) ? pos : neg) + ba * KK;

    const int lane = tid & 63;
    const int half = lane >> 5;                    // 0: even rows, 1: odd rows
    const int slot = lane & 31;                    // float4 slot within row

    const float4* tab4 = (const float4*)table;
    float4 acc = make_float4(0.f, 0.f, 0.f, 0.f);
    #pragma unroll
    for (int i = 0; i < KK / 2; ++i) {
        const int r0 = idx[2 * i];                 // SGPR scalar load
        const int r1 = idx[2 * i + 1];
        const int row = half ? r1 : r0;            // v_cndmask
        const float4 v = tab4[(row << 5) + slot];
        acc.x += v.x; acc.y += v.y; acc.z += v.z; acc.w += v.w;
    }
    acc.x += __shfl_xor(acc.x, 32, 64);
    acc.y += __shfl_xor(acc.y, 32, 64);
    acc.z += __shfl_xor(acc.z, 32, 64);
    acc.w += __shfl_xor(acc.w, 32, 64);

    const float s = 1.0f / MAX_KP;
    acc.x *= s; acc.y *= s; acc.z *= s; acc.w *= s;

    float sq = dot4(acc, acc);
    #pragma unroll
    for (int off = 16; off > 0; off >>= 1) sq += __shfl_xor(sq, off, 64);

    const float inv = 1.0f / fmaxf(sqrtf(sq), EPS_CS);
    acc.x *= inv; acc.y *= inv; acc.z *= inv; acc.w *= inv;

    if (lane < 32)
        ((float4*)embs)[(vec << 5) + slot] = acc;

    // ---- completion: is this the 48th finished block of batch b? ----
    __syncthreads();
    const int b = ((blockIdx.x << 1) & 2047) >> 5;   // same for both waves
    __shared__ int s_win;
    if (tid == 0) {
        __threadfence();                             // publish embs writes
        const unsigned old = __hip_atomic_fetch_add(
            &cnt[b], 1u, __ATOMIC_ACQ_REL, __HIP_MEMORY_SCOPE_AGENT);
        s_win = (old == 47u);
    }
    __syncthreads();
    if (!s_win) return;
    __threadfence();                                 // acquire side

    // ---- cosine for batch b: 128 threads, 2 src rows x 4 tgt cols each ----
    const float4* e4   = (const float4*)embs;
    const int ib = tid >> 3;                         // 0..15 -> rows ib, ib+16
    const int jc = tid & 7;                          // cols jc+8c
    const float4* srcA = e4 + (b * AA + ib) * 32;
    const float4* srcB = srcA + 16 * 32;
    const float4* posR = e4 + (2048 + b * AA) * 32;
    const float4* negR = e4 + (4096 + b * AA) * 32;

    float p[2][4] = {}, n[2][4] = {};
    for (int d = 0; d < 32; ++d) {                   // float4 chunks of D
        const float4 a0 = srcA[d];
        const float4 a1 = srcB[d];
        #pragma unroll
        for (int c = 0; c < 4; ++c) {
            const float4 pv = posR[(jc + 8 * c) * 32 + d];
            const float4 nv = negR[(jc + 8 * c) * 32 + d];
            p[0][c] += dot4(a0, pv); p[1][c] += dot4(a1, pv);
            n[0][c] += dot4(a0, nv); n[1][c] += dot4(a1, nv);
        }
    }
    float pmax = -1e30f, nmax = -1e30f;
    #pragma unroll
    for (int r = 0; r < 2; ++r)
        #pragma unroll
        for (int c = 0; c < 4; ++c) {
            pmax = fmaxf(pmax, p[r][c]);
            nmax = fmaxf(nmax, n[r][c]);
        }
    #pragma unroll
    for (int off = 32; off > 0; off >>= 1) {
        pmax = fmaxf(pmax, __shfl_xor(pmax, off, 64));
        nmax = fmaxf(nmax, __shfl_xor(nmax, off, 64));
    }
    __shared__ float sp[2], sn[2];
    __shared__ int s_fin;
    if ((tid & 63) == 0) { sp[tid >> 6] = pmax; sn[tid >> 6] = nmax; }
    __syncthreads();

    if (tid == 0) {
        const float P = fmaxf(sp[0], sp[1]);
        const float N = fmaxf(sn[0], sn[1]);
        const float x = P - N;
        const float l = (x >= 0.f) ? log1pf(expf(-x)) : (-x + log1pf(expf(x)));
        per_batch[b] = l;
        __threadfence();
        const unsigned o2 = __hip_atomic_fetch_add(
            &cnt[BB], 1u, __ATOMIC_ACQ_REL, __HIP_MEMORY_SCOPE_AGENT);
        s_fin = (o2 == BB - 1u);
    }
    __syncthreads();
    if (!s_fin) return;
    __threadfence();

    // ---- final: 64 lanes, fixed xor-tree sum -> mean ----
    if (tid < BB) {
        float l = __hip_atomic_load(&per_batch[tid], __ATOMIC_RELAXED,
                                    __HIP_MEMORY_SCOPE_AGENT);
        #pragma unroll
        for (int off = 32; off > 0; off >>= 1) l += __shfl_xor(l, off, 64);
        if (tid == 0) out[0] = l * (1.0f / BB);
    }
}

extern "C" void kernel_launch(void* const* d_in, const int* in_sizes, int n_in,
                              void* d_out, int out_size, void* d_ws, size_t ws_size,
                              hipStream_t stream) {
    const int*   batch_source = (const int*)d_in[0];
    const int*   pos_result   = (const int*)d_in[1];
    const int*   neg_result   = (const int*)d_in[2];
    const float* emb_table    = (const float*)d_in[3];
    float* out = (float*)d_out;

    float*    embs      = (float*)d_ws;                 // 3*64*32*128 f32 = 3 MB
    float*    per_batch = embs + 3L * BB * AA * DD;     // 64 f32
    unsigned* cnt       = (unsigned*)(per_batch + BB);  // 65 u32

    init_kernel<<<1, 128, 0, stream>>>(cnt);
    fused_kernel<<<NVEC / 2, 128, 0, stream>>>(
        batch_source, pos_result, neg_result, emb_table,
        embs, cnt, per_batch, out);
}

// Round 7
// 40.436 us; speedup vs baseline: 7.1809x; 7.1809x over previous
//
#include <hip/hip_runtime.h>
#include <math.h>

#define BB 64
#define AA 32
#define KK 50
#define DD 128
#define MAX_KP 50
#define EPS_CS 1e-8f
#define NVEC (3 * BB * AA)   // 6144
#define NCOS (8 * BB)        // 512 cosine blocks

__device__ __forceinline__ float dot4(float4 a, float4 b) {
    return a.x * b.x + a.y * b.y + a.z * b.z + a.w * b.w;
}

// One 64-lane wave per (tensor, b, a) vector; 2 waves per block.
// Gather instruction i loads TWO rows at once via per-lane addresses:
// lanes 0-31 read row idx[2i], lanes 32-63 read row idx[2i+1], 16B/lane.
// Block 0 also resets the completion counter (plain store; kernel-boundary
// ordering publishes it to the next kernel — no fence in the hot path).
__global__ __launch_bounds__(128) void embed_norm_kernel(
    const int* __restrict__ src, const int* __restrict__ pos,
    const int* __restrict__ neg, const float* __restrict__ table,
    float* __restrict__ out, unsigned* __restrict__ cnt)
{
    if (blockIdx.x == 0 && threadIdx.x == 0) cnt[0] = 0u;

    const int vec = __builtin_amdgcn_readfirstlane(
        (blockIdx.x << 1) | (threadIdx.x >> 6));   // 0..6143, wave-uniform
    const int t  = vec >> 11;                      // / (BB*AA = 2048)
    const int ba = vec & 2047;
    const int* idx = ((t == 0) ? src : (t == 1) ? pos : neg) + ba * KK;

    const int lane = threadIdx.x & 63;
    const int half = lane >> 5;                    // 0: even rows, 1: odd rows
    const int slot = lane & 31;                    // float4 slot within the row

    const float4* tab4 = (const float4*)table;
    float4 acc = make_float4(0.f, 0.f, 0.f, 0.f);
    #pragma unroll
    for (int i = 0; i < KK / 2; ++i) {
        const int r0 = idx[2 * i];                 // SGPR (scalar load)
        const int r1 = idx[2 * i + 1];             // SGPR
        const int row = half ? r1 : r0;            // v_cndmask
        const float4 v = tab4[(row << 5) + slot];  // 16B/lane, 1KB/instr
        acc.x += v.x; acc.y += v.y; acc.z += v.z; acc.w += v.w;
    }

    acc.x += __shfl_xor(acc.x, 32, 64);
    acc.y += __shfl_xor(acc.y, 32, 64);
    acc.z += __shfl_xor(acc.z, 32, 64);
    acc.w += __shfl_xor(acc.w, 32, 64);

    const float s = 1.0f / MAX_KP;
    acc.x *= s; acc.y *= s; acc.z *= s; acc.w *= s;

    float sq = dot4(acc, acc);
    #pragma unroll
    for (int off = 16; off > 0; off >>= 1) sq += __shfl_xor(sq, off, 64);

    const float inv = 1.0f / fmaxf(sqrtf(sq), EPS_CS);
    acc.x *= inv; acc.y *= inv; acc.z *= inv; acc.w *= inv;

    if (lane < 32)
        ((float4*)out)[(vec << 5) + slot] = acc;
}

// 8 blocks per batch: q = {pos/neg} x {i-half} x {j-half}. Each block stages
// 16 src + 16 tgt rows (rows padded to DD+4 -> b128 reads, <=2-way conflicts),
// computes its 16x16 dots, max-reduces, publishes a bypass partial + one
// ACQ_REL increment AT BLOCK EXIT (compute fully done -> no cache thrash).
// The 512th finisher loads all partials lane-parallel and writes the loss.
__global__ __launch_bounds__(256) void cosine_loss_kernel(
    const float* __restrict__ embs, float* __restrict__ part /* [BB][8] */,
    unsigned* __restrict__ cnt, float* __restrict__ out)
{
    const int blk  = blockIdx.x;         // 0..511
    const int b    = blk >> 3;
    const int q    = blk & 7;
    const int tens = q >> 2;             // 0 = pos, 1 = neg
    const int ih   = (q >> 1) & 1;       // src half
    const int jh   = q & 1;              // tgt half
    const int tid  = threadIdx.x;

    __shared__ float s_src[16][DD + 4];
    __shared__ float s_tgt[16][DD + 4];

    const float4* src4 = (const float4*)(embs + ((long)b * AA + ih * 16) * DD);
    const float4* tgt4 = (const float4*)(embs +
                          ((long)(BB + tens * BB + b) * AA + jh * 16) * DD);

    for (int i = tid; i < 16 * DD / 4; i += 256) {   // 512 float4s each
        const int r = i >> 5, c = i & 31;
        *(float4*)&s_src[r][c * 4] = src4[i];
        *(float4*)&s_tgt[r][c * 4] = tgt4[i];
    }
    __syncthreads();

    const int si = tid >> 4;             // 0..15 src row
    const int j  = tid & 15;             // 0..15 tgt row

    float dsum = 0.f;
    #pragma unroll 8
    for (int d0 = 0; d0 < DD; d0 += 4)
        dsum += dot4(*(const float4*)&s_src[si][d0],
                     *(const float4*)&s_tgt[j][d0]);

    float m = dsum;
    #pragma unroll
    for (int off = 32; off > 0; off >>= 1) m = fmaxf(m, __shfl_xor(m, off, 64));
    __shared__ float sm[4];
    __shared__ int s_win;
    if ((tid & 63) == 0) sm[tid >> 6] = m;
    __syncthreads();

    if (tid == 0) {
        const float bm = fmaxf(fmaxf(sm[0], sm[1]), fmaxf(sm[2], sm[3]));
        // bypass store to coherence point, then release-ordered increment
        __hip_atomic_store(&part[blk], bm, __ATOMIC_RELAXED,
                           __HIP_MEMORY_SCOPE_AGENT);
        const unsigned old = __hip_atomic_fetch_add(
            cnt, 1u, __ATOMIC_ACQ_REL, __HIP_MEMORY_SCOPE_AGENT);
        s_win = (old == NCOS - 1);
    }
    __syncthreads();
    if (!s_win) return;

    // ---- winner: lane b handles batch b; 8 parallel bypass loads ----
    if (tid < BB) {
        float v[8];
        v[0] = __hip_atomic_load(&part[tid * 8 + 0], __ATOMIC_ACQUIRE,
                                 __HIP_MEMORY_SCOPE_AGENT);
        #pragma unroll
        for (int k = 1; k < 8; ++k)
            v[k] = __hip_atomic_load(&part[tid * 8 + k], __ATOMIC_RELAXED,
                                     __HIP_MEMORY_SCOPE_AGENT);
        const float P = fmaxf(fmaxf(v[0], v[1]), fmaxf(v[2], v[3]));
        const float N = fmaxf(fmaxf(v[4], v[5]), fmaxf(v[6], v[7]));
        const float x = P - N;
        float l = (x >= 0.f) ? log1pf(expf(-x)) : (-x + log1pf(expf(x)));
        #pragma unroll
        for (int off = 32; off > 0; off >>= 1) l += __shfl_xor(l, off, 64);
        if (tid == 0) out[0] = l * (1.0f / BB);
    }
}

extern "C" void kernel_launch(void* const* d_in, const int* in_sizes, int n_in,
                              void* d_out, int out_size, void* d_ws, size_t ws_size,
                              hipStream_t stream) {
    const int*   batch_source = (const int*)d_in[0];
    const int*   pos_result   = (const int*)d_in[1];
    const int*   neg_result   = (const int*)d_in[2];
    const float* emb_table    = (const float*)d_in[3];
    float* out = (float*)d_out;

    float*    embs = (float*)d_ws;                  // 3*64*32*128 f32 = 3 MB
    float*    part = embs + 3L * BB * AA * DD;      // 512 f32
    unsigned* cnt  = (unsigned*)(part + NCOS);      // 1 u32

    embed_norm_kernel<<<NVEC / 2, 128, 0, stream>>>(
        batch_source, pos_result, neg_result, emb_table, embs, cnt);
    cosine_loss_kernel<<<NCOS, 256, 0, stream>>>(embs, part, cnt, out);
}

// Round 8
// 34.107 us; speedup vs baseline: 8.5134x; 1.1856x over previous
//
#include <hip/hip_runtime.h>
#include <math.h>

#define BB 64
#define AA 32
#define KK 50
#define DD 128
#define MAX_KP 50
#define EPS_CS 1e-8f
#define NVEC (3 * BB * AA)   // 6144

__device__ __forceinline__ float dot4(float4 a, float4 b) {
    return a.x * b.x + a.y * b.y + a.z * b.z + a.w * b.w;
}

// One 64-lane wave per (tensor, b, a) vector; 2 waves per 128-thread block.
// Gather instruction i loads TWO rows at once via per-lane addresses:
// lanes 0-31 read row idx[2i], lanes 32-63 read row idx[2i+1], 16B/lane
// (global_load_dwordx4, 1024B per instruction). Indices come from scalar
// (SGPR) loads; row select is one v_cndmask. 25 loads/wave for 50 rows.
// Measured: this kernel sits at the L2<->L3/HBM fabric service floor
// (~145 MB cross-fabric at ~6 TB/s); halving instruction count (R4->R5)
// changed nothing, and fence/atomic fusion attempts (R6/R7) regressed.
__global__ __launch_bounds__(128) void embed_norm_kernel(
    const int* __restrict__ src, const int* __restrict__ pos,
    const int* __restrict__ neg, const float* __restrict__ table,
    float* __restrict__ out)
{
    const int vec = __builtin_amdgcn_readfirstlane(
        (blockIdx.x << 1) | (threadIdx.x >> 6));   // 0..6143, wave-uniform
    const int t  = vec >> 11;                      // / (BB*AA = 2048)
    const int ba = vec & 2047;
    const int* idx = ((t == 0) ? src : (t == 1) ? pos : neg) + ba * KK;

    const int lane = threadIdx.x & 63;
    const int half = lane >> 5;                    // 0: even rows, 1: odd rows
    const int slot = lane & 31;                    // float4 slot within the row

    const float4* tab4 = (const float4*)table;
    float4 acc = make_float4(0.f, 0.f, 0.f, 0.f);
    #pragma unroll
    for (int i = 0; i < KK / 2; ++i) {
        const int r0 = idx[2 * i];                 // SGPR (scalar load)
        const int r1 = idx[2 * i + 1];             // SGPR
        const int row = half ? r1 : r0;            // v_cndmask
        const float4 v = tab4[(row << 5) + slot];  // 32-bit offset, 16B/lane
        acc.x += v.x; acc.y += v.y; acc.z += v.z; acc.w += v.w;
    }

    // combine the two half-wave partials (each lane pairs with lane^32)
    acc.x += __shfl_xor(acc.x, 32, 64);
    acc.y += __shfl_xor(acc.y, 32, 64);
    acc.z += __shfl_xor(acc.z, 32, 64);
    acc.w += __shfl_xor(acc.w, 32, 64);

    const float s = 1.0f / MAX_KP;
    acc.x *= s; acc.y *= s; acc.z *= s; acc.w *= s;

    float sq = dot4(acc, acc);
    #pragma unroll
    for (int off = 16; off > 0; off >>= 1) sq += __shfl_xor(sq, off, 64);

    const float inv = 1.0f / fmaxf(sqrtf(sq), EPS_CS);
    acc.x *= inv; acc.y *= inv; acc.z *= inv; acc.w *= inv;

    if (lane < 32)
        ((float4*)out)[(vec << 5) + slot] = acc;
}

// 4 blocks per batch: q = {pos/neg} x {i-half}. Each block stages 16 src rows
// + 32 tgt rows (rows padded to 132 floats -> b128 reads, <=2-way conflicts),
// computes max over its 16x32 dots, writes a partial max.
__global__ __launch_bounds__(256) void cosine_part_kernel(
    const float* __restrict__ embs, float* __restrict__ part /* [BB][4] */)
{
    const int blk = blockIdx.x;          // 0..255
    const int b   = blk >> 2;
    const int q   = blk & 3;
    const int tens  = q >> 1;            // 0 = pos, 1 = neg
    const int ihalf = q & 1;             // which 16 src rows
    const int tid = threadIdx.x;

    __shared__ float s_src[16][DD + 4];
    __shared__ float s_tgt[AA][DD + 4];

    const float4* src4 = (const float4*)(embs + ((long)b * AA + ihalf * 16) * DD);
    const float4* tgt4 = (const float4*)(embs + (long)(BB + tens * BB + b) * AA * DD);

    for (int i = tid; i < 16 * DD / 4; i += 256) {   // 512 float4s
        const int r = i >> 5, c = i & 31;
        *(float4*)&s_src[r][c * 4] = src4[i];
    }
    for (int i = tid; i < AA * DD / 4; i += 256) {   // 1024 float4s
        const int r = i >> 5, c = i & 31;
        *(float4*)&s_tgt[r][c * 4] = tgt4[i];
    }
    __syncthreads();

    const int si = tid >> 4;             // 0..15 src row
    const int j  = tid & 15;             // tgt cols j, j+16

    float d0s = 0.f, d1s = 0.f;
    #pragma unroll 8
    for (int d0 = 0; d0 < DD; d0 += 4) {
        const float4 a  = *(const float4*)&s_src[si][d0];
        const float4 t0 = *(const float4*)&s_tgt[j][d0];
        const float4 t1 = *(const float4*)&s_tgt[j + 16][d0];
        d0s += dot4(a, t0);
        d1s += dot4(a, t1);
    }
    float m = fmaxf(d0s, d1s);

    #pragma unroll
    for (int off = 32; off > 0; off >>= 1) m = fmaxf(m, __shfl_xor(m, off, 64));
    __shared__ float sm[4];
    if ((tid & 63) == 0) sm[tid >> 6] = m;
    __syncthreads();

    if (tid == 0)
        part[blk] = fmaxf(fmaxf(sm[0], sm[1]), fmaxf(sm[2], sm[3]));
}

// One wave: lane b -> loss_b, wave-reduce fixed-order sum -> mean.
__global__ void finalize_kernel(const float* __restrict__ part,
                                float* __restrict__ out)
{
    const int b = threadIdx.x;           // 0..63
    const float P = fmaxf(part[b * 4 + 0], part[b * 4 + 1]);
    const float N = fmaxf(part[b * 4 + 2], part[b * 4 + 3]);
    const float x = P - N;
    float l = (x >= 0.f) ? log1pf(expf(-x)) : (-x + log1pf(expf(x)));
    #pragma unroll
    for (int off = 32; off > 0; off >>= 1) l += __shfl_xor(l, off, 64);
    if (b == 0) out[0] = l * (1.0f / BB);
}

extern "C" void kernel_launch(void* const* d_in, const int* in_sizes, int n_in,
                              void* d_out, int out_size, void* d_ws, size_t ws_size,
                              hipStream_t stream) {
    const int*   batch_source = (const int*)d_in[0];
    const int*   pos_result   = (const int*)d_in[1];
    const int*   neg_result   = (const int*)d_in[2];
    const float* emb_table    = (const float*)d_in[3];
    float* out = (float*)d_out;

    float* embs = (float*)d_ws;                     // 3*64*32*128 f32 = 3 MB
    float* part = embs + 3L * BB * AA * DD;         // 256 f32

    embed_norm_kernel<<<NVEC / 2, 128, 0, stream>>>(
        batch_source, pos_result, neg_result, emb_table, embs);
    cosine_part_kernel<<<4 * BB, 256, 0, stream>>>(embs, part);
    finalize_kernel<<<1, 64, 0, stream>>>(part, out);
}